// Round 1
// baseline (539.663 us; speedup 1.0000x reference)
//
#include <hip/hip_runtime.h>
#include <math.h>

#define FEAT 128
#define OUTF 384
#define NRBF 20

// Detect whether nbrs buffer is int64 (little-endian: odd int32 words are the
// high halves, all zero since indices < 50000) or genuine int32 pairs.
__device__ __forceinline__ int nbrs_is_i64(const int* nb) {
    int nz = 0;
#pragma unroll
    for (int i = 1; i < 256; i += 2) nz |= nb[i];
    return nz == 0;
}

// Computes PHI[row] = silu(src_row @ W1 + b1) @ W2 + b2 for 64 rows per block.
// GATHER=false: src row i = s_j[i]      (node mode, dst = PHI workspace)
// GATHER=true : src row i = s_j[nbrs[i,1]] (direct mode, dst = d_out)
template <bool GATHER>
__global__ __launch_bounds__(256) void phi_kernel(
    const float* __restrict__ s_j, const int* __restrict__ nbrs,
    const float* __restrict__ W1, const float* __restrict__ b1,
    const float* __restrict__ W2, const float* __restrict__ b2,
    float* __restrict__ dst, int M)
{
    __shared__ __align__(16) float st[FEAT][66]; // transposed tile [k][row]; reused for h
    const int t = threadIdx.x;
    const int base = blockIdx.x * 64;

    int i64f = 0;
    if (GATHER) i64f = nbrs_is_i64(nbrs);

    // stage s tile (transposed). idx consecutive -> k consecutive -> coalesced.
    for (int idx = t; idx < 64 * FEAT; idx += 256) {
        int n = idx >> 7, k = idx & 127;
        int row = base + n;
        float v = 0.f;
        if (row < M) {
            int src = GATHER ? (i64f ? nbrs[4 * (size_t)row + 2] : nbrs[2 * (size_t)row + 1])
                             : row;
            v = s_j[(size_t)src * FEAT + k];
        }
        st[k][n] = v;
    }
    __syncthreads();

    const int cg = t & 31;  // 32 column groups of 4
    const int rg = t >> 5;  // 8 row groups of 8
    const int c0 = cg * 4;
    const int r0 = rg * 8;

    float acc[8][4];
    // ---- h = silu(s @ W1 + b1), thread tile 8 rows x 4 cols ----
    {
        float4 b = *(const float4*)(b1 + c0);
#pragma unroll
        for (int i = 0; i < 8; i++) { acc[i][0] = b.x; acc[i][1] = b.y; acc[i][2] = b.z; acc[i][3] = b.w; }
        for (int k = 0; k < FEAT; k++) {
            float4 w = *(const float4*)(W1 + (size_t)k * FEAT + c0);
            float2 sa = *(const float2*)(&st[k][r0]);
            float2 sb = *(const float2*)(&st[k][r0 + 2]);
            float2 sc = *(const float2*)(&st[k][r0 + 4]);
            float2 sd = *(const float2*)(&st[k][r0 + 6]);
            float sv[8] = {sa.x, sa.y, sb.x, sb.y, sc.x, sc.y, sd.x, sd.y};
#pragma unroll
            for (int i = 0; i < 8; i++) {
                acc[i][0] += sv[i] * w.x; acc[i][1] += sv[i] * w.y;
                acc[i][2] += sv[i] * w.z; acc[i][3] += sv[i] * w.w;
            }
        }
    }
    __syncthreads();  // all reads of st done before overwriting with h
    // silu + store h transposed into the same LDS buffer
#pragma unroll
    for (int i = 0; i < 8; i++)
#pragma unroll
        for (int j = 0; j < 4; j++) {
            float h = acc[i][j];
            h = h * __frcp_rn(1.f + __expf(-h));
            st[c0 + j][r0 + i] = h;
        }
    __syncthreads();

    // ---- phi = h @ W2 + b2, 3 chunks of 128 cols ----
    for (int ch = 0; ch < 3; ch++) {
        const int oc = ch * 128 + c0;
        float4 b = *(const float4*)(b2 + oc);
#pragma unroll
        for (int i = 0; i < 8; i++) { acc[i][0] = b.x; acc[i][1] = b.y; acc[i][2] = b.z; acc[i][3] = b.w; }
        for (int k = 0; k < FEAT; k++) {
            float4 w = *(const float4*)(W2 + (size_t)k * OUTF + oc);
            float2 ha = *(const float2*)(&st[k][r0]);
            float2 hb = *(const float2*)(&st[k][r0 + 2]);
            float2 hc = *(const float2*)(&st[k][r0 + 4]);
            float2 hd = *(const float2*)(&st[k][r0 + 6]);
            float hv[8] = {ha.x, ha.y, hb.x, hb.y, hc.x, hc.y, hd.x, hd.y};
#pragma unroll
            for (int i = 0; i < 8; i++) {
                acc[i][0] += hv[i] * w.x; acc[i][1] += hv[i] * w.y;
                acc[i][2] += hv[i] * w.z; acc[i][3] += hv[i] * w.w;
            }
        }
#pragma unroll
        for (int i = 0; i < 8; i++) {
            int row = base + r0 + i;
            if (row < M) {
                float4 o = {acc[i][0], acc[i][1], acc[i][2], acc[i][3]};
                *(float4*)(dst + (size_t)row * OUTF + oc) = o;
            }
        }
    }
}

// Per edge: out[e] = phi_row * (rbf(dist[e]) @ Wd + bd)
// 96 threads per edge, each owns 4 output cols; Wd column slice lives in VGPRs.
// rbf via Chebyshev recurrence: sin((n+1)x) = 2cos(x) sin(nx) - sin((n-1)x).
// NOTE: phi/out may alias (direct mode) -> no __restrict__ on them.
__global__ __launch_bounds__(384) void edge_kernel(
    const float* __restrict__ dist, const int* __restrict__ nbrs,
    const float* phi, const float* __restrict__ Wd,
    const float* __restrict__ bd, float* out,
    int E, int gather)
{
    const int g = threadIdx.x / 96;
    const int q = threadIdx.x % 96;
    const int c0 = q * 4;

    float4 wd[NRBF];
#pragma unroll
    for (int k = 0; k < NRBF; k++) wd[k] = *(const float4*)(Wd + (size_t)k * OUTF + c0);
    float4 bdr = *(const float4*)(bd + c0);

    int i64f = gather ? nbrs_is_i64(nbrs) : 0;
    const float kx = (float)(M_PI / 5.0);

    for (long long e = (long long)blockIdx.x * 4 + g; e < E; e += (long long)gridDim.x * 4) {
        float d = dist[e];
        float x = d * kx;
        float s1 = __sinf(x), c1 = __cosf(x);
        float t2c = 2.f * c1;
        float sp = 0.f, sc = s1;
        float ax = 0.f, ay = 0.f, az = 0.f, aw = 0.f;
#pragma unroll
        for (int n = 0; n < NRBF; n++) {
            ax += sc * wd[n].x; ay += sc * wd[n].y;
            az += sc * wd[n].z; aw += sc * wd[n].w;
            float sn = t2c * sc - sp; sp = sc; sc = sn;
        }
        float rd = __frcp_rn(d);
        long long row = gather ? (long long)(i64f ? nbrs[4 * e + 2] : nbrs[2 * e + 1]) : e;
        const float4 p = *(const float4*)(phi + row * OUTF + c0);
        float4 o;
        o.x = p.x * (ax * rd + bdr.x);
        o.y = p.y * (ay * rd + bdr.y);
        o.z = p.z * (az * rd + bdr.z);
        o.w = p.w * (aw * rd + bdr.w);
        *(float4*)(out + e * OUTF + c0) = o;
    }
}

extern "C" void kernel_launch(void* const* d_in, const int* in_sizes, int n_in,
                              void* d_out, int out_size, void* d_ws, size_t ws_size,
                              hipStream_t stream)
{
    const float* s_j  = (const float*)d_in[0];
    const float* dist = (const float*)d_in[1];
    const int*   nbrs = (const int*)d_in[2];
    const float* W1   = (const float*)d_in[3];
    const float* b1   = (const float*)d_in[4];
    const float* W2   = (const float*)d_in[5];
    const float* b2   = (const float*)d_in[6];
    const float* Wd   = (const float*)d_in[7];
    const float* bd   = (const float*)d_in[8];
    float* out = (float*)d_out;

    const int N = in_sizes[0] / FEAT;
    const int E = in_sizes[1];
    if (E <= 0) return;

    const size_t phi_bytes = (size_t)N * OUTF * sizeof(float);
    int egrid = (E + 3) / 4;
    if (egrid > 2048) egrid = 2048;

    if (ws_size >= phi_bytes) {
        // node-level precompute: PHI (N x 384) in workspace, then edge scale
        float* PHI = (float*)d_ws;
        dim3 gA((N + 63) / 64);
        phi_kernel<false><<<gA, 256, 0, stream>>>(s_j, nbrs, W1, b1, W2, b2, PHI, N);
        edge_kernel<<<egrid, 384, 0, stream>>>(dist, nbrs, PHI, Wd, bd, out, E, 1);
    } else {
        // fallback: per-edge phi directly into d_out, then scale in place
        dim3 gA((E + 63) / 64);
        phi_kernel<true><<<gA, 256, 0, stream>>>(s_j, nbrs, W1, b1, W2, b2, out, E);
        edge_kernel<<<egrid, 384, 0, stream>>>(dist, nbrs, out, Wd, bd, out, E, 0);
    }
}

// Round 2
// 517.901 us; speedup vs baseline: 1.0420x; 1.0420x over previous
//
#include <hip/hip_runtime.h>
#include <math.h>

#define FEAT 128
#define OUTF 384
#define NRBF 20

typedef float f32x4 __attribute__((ext_vector_type(4)));

// Detect whether nbrs buffer is int64 (little-endian: odd int32 words are the
// high halves, all zero since indices < 50000) or genuine int32 pairs.
// 32 odd words all-zero by chance in int32 mode is impossible in practice.
__device__ __forceinline__ int nbrs_is_i64(const int* nb) {
    int nz = 0;
#pragma unroll
    for (int i = 1; i < 64; i += 2) nz |= nb[i];
    return nz == 0;
}

// Computes PHI[row] = silu(src_row @ W1 + b1) @ W2 + b2 for 64 rows per block.
// GATHER=false: src row i = s_j[i]      (node mode, dst = PHI workspace)
// GATHER=true : src row i = s_j[nbrs[i,1]] (direct mode, dst = d_out)
template <bool GATHER>
__global__ __launch_bounds__(256) void phi_kernel(
    const float* __restrict__ s_j, const int* __restrict__ nbrs,
    const float* __restrict__ W1, const float* __restrict__ b1,
    const float* __restrict__ W2, const float* __restrict__ b2,
    float* __restrict__ dst, int M)
{
    __shared__ __align__(16) float st[FEAT][66]; // transposed tile [k][row]; reused for h
    const int t = threadIdx.x;
    const int base = blockIdx.x * 64;

    int i64f = 0;
    if (GATHER) i64f = nbrs_is_i64(nbrs);

    // stage s tile (transposed). idx consecutive -> k consecutive -> coalesced.
    for (int idx = t; idx < 64 * FEAT; idx += 256) {
        int n = idx >> 7, k = idx & 127;
        int row = base + n;
        float v = 0.f;
        if (row < M) {
            int src = GATHER ? (i64f ? nbrs[4 * (size_t)row + 2] : nbrs[2 * (size_t)row + 1])
                             : row;
            v = s_j[(size_t)src * FEAT + k];
        }
        st[k][n] = v;
    }
    __syncthreads();

    const int cg = t & 31;  // 32 column groups of 4
    const int rg = t >> 5;  // 8 row groups of 8
    const int c0 = cg * 4;
    const int r0 = rg * 8;

    float acc[8][4];
    // ---- h = silu(s @ W1 + b1), thread tile 8 rows x 4 cols ----
    {
        float4 b = *(const float4*)(b1 + c0);
#pragma unroll
        for (int i = 0; i < 8; i++) { acc[i][0] = b.x; acc[i][1] = b.y; acc[i][2] = b.z; acc[i][3] = b.w; }
        for (int k = 0; k < FEAT; k++) {
            float4 w = *(const float4*)(W1 + (size_t)k * FEAT + c0);
            float2 sa = *(const float2*)(&st[k][r0]);
            float2 sb = *(const float2*)(&st[k][r0 + 2]);
            float2 sc = *(const float2*)(&st[k][r0 + 4]);
            float2 sd = *(const float2*)(&st[k][r0 + 6]);
            float sv[8] = {sa.x, sa.y, sb.x, sb.y, sc.x, sc.y, sd.x, sd.y};
#pragma unroll
            for (int i = 0; i < 8; i++) {
                acc[i][0] += sv[i] * w.x; acc[i][1] += sv[i] * w.y;
                acc[i][2] += sv[i] * w.z; acc[i][3] += sv[i] * w.w;
            }
        }
    }
    __syncthreads();  // all reads of st done before overwriting with h
    // silu + store h transposed into the same LDS buffer
#pragma unroll
    for (int i = 0; i < 8; i++)
#pragma unroll
        for (int j = 0; j < 4; j++) {
            float h = acc[i][j];
            h = h * __frcp_rn(1.f + __expf(-h));
            st[c0 + j][r0 + i] = h;
        }
    __syncthreads();

    // ---- phi = h @ W2 + b2, 3 chunks of 128 cols ----
    for (int ch = 0; ch < 3; ch++) {
        const int oc = ch * 128 + c0;
        float4 b = *(const float4*)(b2 + oc);
#pragma unroll
        for (int i = 0; i < 8; i++) { acc[i][0] = b.x; acc[i][1] = b.y; acc[i][2] = b.z; acc[i][3] = b.w; }
        for (int k = 0; k < FEAT; k++) {
            float4 w = *(const float4*)(W2 + (size_t)k * OUTF + oc);
            float2 ha = *(const float2*)(&st[k][r0]);
            float2 hb = *(const float2*)(&st[k][r0 + 2]);
            float2 hc = *(const float2*)(&st[k][r0 + 4]);
            float2 hd = *(const float2*)(&st[k][r0 + 6]);
            float hv[8] = {ha.x, ha.y, hb.x, hb.y, hc.x, hc.y, hd.x, hd.y};
#pragma unroll
            for (int i = 0; i < 8; i++) {
                acc[i][0] += hv[i] * w.x; acc[i][1] += hv[i] * w.y;
                acc[i][2] += hv[i] * w.z; acc[i][3] += hv[i] * w.w;
            }
        }
#pragma unroll
        for (int i = 0; i < 8; i++) {
            int row = base + r0 + i;
            if (row < M) {
                float4 o = {acc[i][0], acc[i][1], acc[i][2], acc[i][3]};
                *(float4*)(dst + (size_t)row * OUTF + oc) = o;
            }
        }
    }
}

// Per edge: out[e] = phi_row * (rbf(dist[e]) @ Wd + bd)
// 96 threads per edge, each owns 4 output cols; Wd column slice lives in VGPRs.
// Each thread handles TWO consecutive edges per iteration (2 gathers in
// flight, 2 independent sin-recurrence chains).
// rbf via Chebyshev recurrence: sin((n+1)x) = 2cos(x) sin(nx) - sin((n-1)x).
// out is written with NON-TEMPORAL stores so the 921.6 MB write stream does
// not evict the PHI table (76.8 MB) from L2/L3 — gathers then hit cache.
// NOTE: phi/out may alias (direct mode) -> no __restrict__ on them.
__global__ __launch_bounds__(384, 3) void edge_kernel(
    const float* __restrict__ dist, const int* __restrict__ nbrs,
    const float* phi, const float* __restrict__ Wd,
    const float* __restrict__ bd, float* out,
    int E, int gather)
{
    const int g = threadIdx.x / 96;
    const int q = threadIdx.x % 96;
    const int c0 = q * 4;

    f32x4 wd[NRBF];
#pragma unroll
    for (int k = 0; k < NRBF; k++) wd[k] = *(const f32x4*)(Wd + (size_t)k * OUTF + c0);
    f32x4 bdr = *(const f32x4*)(bd + c0);

    int i64f = gather ? nbrs_is_i64(nbrs) : 0;
    const float kx = (float)(M_PI / 5.0);
    const long long stride = (long long)gridDim.x * 8;

    for (long long e = (long long)blockIdx.x * 8 + g * 2; e < E; e += stride) {
        const bool has1 = (e + 1 < E);
        float d0 = __builtin_nontemporal_load(dist + e);
        float d1 = has1 ? __builtin_nontemporal_load(dist + e + 1) : 1.f;
        long long r0, r1;
        if (gather) {
            r0 = i64f ? nbrs[4 * e + 2] : nbrs[2 * e + 1];
            r1 = has1 ? (i64f ? nbrs[4 * e + 6] : nbrs[2 * e + 3]) : r0;
        } else { r0 = e; r1 = has1 ? e + 1 : r0; }
        // issue both gathers before the recurrences
        const f32x4 p0 = *(const f32x4*)(phi + r0 * OUTF + c0);
        const f32x4 p1 = *(const f32x4*)(phi + r1 * OUTF + c0);

        float x0 = d0 * kx, x1 = d1 * kx;
        float s0 = __sinf(x0), cc0 = __cosf(x0);
        float s1 = __sinf(x1), cc1 = __cosf(x1);
        float t0 = 2.f * cc0, t1 = 2.f * cc1;
        float sp0 = 0.f, sc0 = s0;
        float sp1 = 0.f, sc1 = s1;
        f32x4 a0 = {0.f, 0.f, 0.f, 0.f};
        f32x4 a1 = {0.f, 0.f, 0.f, 0.f};
#pragma unroll
        for (int n = 0; n < NRBF; n++) {
            a0 += sc0 * wd[n];
            a1 += sc1 * wd[n];
            float n0 = t0 * sc0 - sp0; sp0 = sc0; sc0 = n0;
            float n1 = t1 * sc1 - sp1; sp1 = sc1; sc1 = n1;
        }
        float rd0 = __frcp_rn(d0), rd1 = __frcp_rn(d1);
        f32x4 o0 = p0 * (a0 * rd0 + bdr);
        __builtin_nontemporal_store(o0, (f32x4*)(out + e * OUTF + c0));
        if (has1) {
            f32x4 o1 = p1 * (a1 * rd1 + bdr);
            __builtin_nontemporal_store(o1, (f32x4*)(out + (e + 1) * OUTF + c0));
        }
    }
}

extern "C" void kernel_launch(void* const* d_in, const int* in_sizes, int n_in,
                              void* d_out, int out_size, void* d_ws, size_t ws_size,
                              hipStream_t stream)
{
    const float* s_j  = (const float*)d_in[0];
    const float* dist = (const float*)d_in[1];
    const int*   nbrs = (const int*)d_in[2];
    const float* W1   = (const float*)d_in[3];
    const float* b1   = (const float*)d_in[4];
    const float* W2   = (const float*)d_in[5];
    const float* b2   = (const float*)d_in[6];
    const float* Wd   = (const float*)d_in[7];
    const float* bd   = (const float*)d_in[8];
    float* out = (float*)d_out;

    const int N = in_sizes[0] / FEAT;
    const int E = in_sizes[1];
    if (E <= 0) return;

    const size_t phi_bytes = (size_t)N * OUTF * sizeof(float);
    int egrid = (E + 7) / 8;
    if (egrid > 2048) egrid = 2048;

    if (ws_size >= phi_bytes) {
        // node-level precompute: PHI (N x 384) in workspace, then edge scale
        float* PHI = (float*)d_ws;
        dim3 gA((N + 63) / 64);
        phi_kernel<false><<<gA, 256, 0, stream>>>(s_j, nbrs, W1, b1, W2, b2, PHI, N);
        edge_kernel<<<egrid, 384, 0, stream>>>(dist, nbrs, PHI, Wd, bd, out, E, 1);
    } else {
        // fallback: per-edge phi directly into d_out, then scale in place
        dim3 gA((E + 63) / 64);
        phi_kernel<true><<<gA, 256, 0, stream>>>(s_j, nbrs, W1, b1, W2, b2, out, E);
        edge_kernel<<<egrid, 384, 0, stream>>>(dist, nbrs, out, Wd, bd, out, E, 0);
    }
}